// Round 17
// baseline (101.010 us; speedup 1.0000x reference)
//
#include <hip/hip_runtime.h>
#include <stdint.h>

typedef __bf16 bf16x8 __attribute__((ext_vector_type(8)));
typedef float  f32x4  __attribute__((ext_vector_type(4)));
typedef float  f32x16 __attribute__((ext_vector_type(16)));
typedef unsigned short u16;
typedef unsigned int   u32;

#define B_  2
#define S_  2048
#define H_  1024
#define NH_ 16
#define HD_ 64
#define QSCL 0.18033688011112042f  /* 0.125 * log2(e) */

__device__ __forceinline__ u16 f2bf(float f) {
  u32 u = __builtin_bit_cast(u32, f);
  return (u16)((u + 0x7FFFu + ((u >> 16) & 1u)) >> 16);
}
__device__ __forceinline__ float ex2(float x) { return __builtin_amdgcn_exp2f(x); }
__device__ __forceinline__ u32 cvtpk(float lo, float hi) {
  u32 r; asm("v_cvt_pk_bf16_f32 %0, %1, %2" : "=v"(r) : "v"(lo), "v"(hi)); return r;
}
__device__ __forceinline__ void gload_lds16(const u16* g, u16* lds) {
  __builtin_amdgcn_global_load_lds(
      (__attribute__((address_space(1))) void*)(void*)g,
      (__attribute__((address_space(3))) void*)lds, 16, 0, 0);
}
#define SBAR() asm volatile("s_barrier" ::: "memory")

__global__ void cvt_all(const float* __restrict__ a, const float* __restrict__ b,
                        const float* __restrict__ c, u16* __restrict__ oa,
                        u16* __restrict__ ob, u16* __restrict__ oc) {
  int i = blockIdx.x * 256 + threadIdx.x;
  const float4* src; ushort4* dst; int j;
  if (i < 1048576)      { src = (const float4*)a; dst = (ushort4*)oa; j = i; }
  else if (i < 1835008) { src = (const float4*)b; dst = (ushort4*)ob; j = i - 1048576; }
  else                  { src = (const float4*)c; dst = (ushort4*)oc; j = i - 1835008; }
  const float4 v = src[j];
  ushort4 o;
  o.x = f2bf(v.x); o.y = f2bf(v.y); o.z = f2bf(v.z); o.w = f2bf(v.w);
  dst[j] = o;
}

// QKV GEMM, TRIPLE-BUFFERED counted-vmcnt (T4): BM=128 x BN=192, BK=64,
// 512 thr / 8 waves (2m x 4n), per-wave C = 64x48. Loads for tile t+2 issued
// during iter t; end-of-iter s_waitcnt vmcnt(5) waits ONLY tile t+1's 5
// loads while t+2's stay in flight -> full-iteration latency cover. ONE
// s_barrier per K-tile. Buffer (t+2)%3's last reads were iter t-1, sealed by
// that barrier (all waves sit between consecutive barriers -> no rotation
// race). LDS 120KB -> 1 block/CU. Fused V-transpose epilogue (Vt aliases
// dead staging LDS). q pre-scaled by QSCL (load-bearing!).
__global__ __launch_bounds__(512, 1)
void gemm_qkv(const u16* __restrict__ A, const u16* __restrict__ W,
              const float* __restrict__ bias,
              u16* __restrict__ qb, u16* __restrict__ kb, u16* __restrict__ vtb)
{
  __shared__ __align__(16) u16 smem[61440];   // 120 KB: A bufs @ i*8192 (128x64), B bufs @ 24576+i*12288 (192x64)
  u16* const Vt = smem;                        // [192][136] alias, post-loop
  const int K = 1024;
  const int tid = threadIdx.x;
  const int w = tid >> 6, l = tid & 63;
  const int lg = l >> 4, lr = l & 15;
  const int wm = w >> 2, wn = w & 3;
  const int tM = blockIdx.y * 128, tN = blockIdx.x * 192;

  f32x4 acc[4][3] = {};

  const int srow = tid >> 3;                     // 0..63
  const int scol = ((tid & 7) ^ (srow & 7)) << 3;
  const u16* asrc = A + (size_t)(tM + srow) * K + scol;
  const u16* bsrc = W + (size_t)(tN + srow) * K + scol;

  auto STG = [&](int buf, int k0) {              // 5 gloads (2 A-parts + 3 B-parts)
#pragma unroll
    for (int p = 0; p < 2; ++p)
      gload_lds16(asrc + (size_t)(p * 64) * K + k0, &smem[buf * 8192 + p * 4096 + w * 512]);
#pragma unroll
    for (int p = 0; p < 3; ++p)
      gload_lds16(bsrc + (size_t)(p * 64) * K + k0, &smem[24576 + buf * 12288 + p * 4096 + w * 512]);
  };

  STG(0, 0);
  STG(1, 64);
  asm volatile("s_waitcnt vmcnt(5)" ::: "memory");   // tile 0 landed; tile 1 in flight
  SBAR();

  const int sw = lr & 7;

  int cur = 0;
  for (int t = 0; t < 16; ++t) {
    if (t + 2 < 16) {
      int nb = cur + 2; if (nb >= 3) nb -= 3;
      STG(nb, (t + 2) * 64);
    }
    const int aoff = cur * 8192, boff = 24576 + cur * 12288;

    bf16x8 af[4][2];
#pragma unroll
    for (int m = 0; m < 4; ++m)
#pragma unroll
      for (int kk = 0; kk < 2; ++kk)
        af[m][kk] = *(const bf16x8*)&smem[aoff + (wm * 64 + m * 16 + lr) * 64 +
                                          (((kk * 4 + lg) ^ sw) << 3)];
    __builtin_amdgcn_s_setprio(1);
#pragma unroll
    for (int n = 0; n < 3; ++n) {
      bf16x8 bw0 = *(const bf16x8*)&smem[boff + (wn * 48 + n * 16 + lr) * 64 + (((lg) ^ sw) << 3)];
      bf16x8 bw1 = *(const bf16x8*)&smem[boff + (wn * 48 + n * 16 + lr) * 64 + (((4 + lg) ^ sw) << 3)];
#pragma unroll
      for (int m = 0; m < 4; ++m) {
        acc[m][n] = __builtin_amdgcn_mfma_f32_16x16x32_bf16(af[m][0], bw0, acc[m][n], 0, 0, 0);
        acc[m][n] = __builtin_amdgcn_mfma_f32_16x16x32_bf16(af[m][1], bw1, acc[m][n], 0, 0, 0);
      }
    }
    __builtin_amdgcn_s_setprio(0);

    if (t + 2 < 16)      asm volatile("s_waitcnt vmcnt(5)" ::: "memory");
    else if (t + 1 < 16) asm volatile("s_waitcnt vmcnt(0)" ::: "memory");
    SBAR();
    cur = (cur + 1 == 3) ? 0 : cur + 1;
  }

  // ---- epilogue (after final SBAR: all staging reads retired -> Vt alias safe) ----
  const int bb = tM >> 11, ssb = tM & 2047;
#pragma unroll
  for (int n = 0; n < 3; ++n) {
    const int cl = wn * 48 + n * 16 + lr;
    const int col = tN + cl;
    const float bv = bias[col];
    const int t3 = col >> 10, rem = col & 1023;
    const int hh = rem >> 6, dd = rem & 63;
    if (t3 < 2) {
      const float sc = (t3 == 0) ? QSCL : 1.f;
      u16* dst = (t3 == 0) ? qb : kb;
#pragma unroll
      for (int m = 0; m < 4; ++m)
#pragma unroll
        for (int r = 0; r < 4; ++r) {
          const int rl = wm * 64 + m * 16 + lg * 4 + r;
          dst[((size_t)(bb * NH_ + hh) * S_ + (ssb + rl)) * HD_ + dd] = f2bf((acc[m][n][r] + bv) * sc);
        }
    } else {
#pragma unroll
      for (int m = 0; m < 4; ++m) {
        ushort4 pk;
        pk.x = f2bf(acc[m][n][0] + bv);
        pk.y = f2bf(acc[m][n][1] + bv);
        pk.z = f2bf(acc[m][n][2] + bv);
        pk.w = f2bf(acc[m][n][3] + bv);
        *(ushort4*)&Vt[cl * 136 + wm * 64 + m * 16 + lg * 4] = pk;
      }
    }
  }

  if (tN >= 1920) {                       // block has v columns (bx >= 10)
    __syncthreads();                      // uniform condition -> legal
    const int cl0 = (tN < 2048) ? (2048 - tN) : 0;
    const int nch = (192 - cl0) * 16;     // (col, 8-ss-chunk) pairs
    for (int c = tid; c < nch; c += 512) {
      const int cv = cl0 + (c >> 4), ch = c & 15;
      const int rem = (tN + cv) & 1023;
      const int hh2 = rem >> 6, dd2 = rem & 63;
      const uint4 v = *(const uint4*)&Vt[cv * 136 + ch * 8];
      *(uint4*)&vtb[((size_t)(bb * NH_ + hh2) * HD_ + dd2) * S_ + ssb + ch * 8] = v;
    }
  }
}

// Out-proj (R14 structure, frozen): BM=128 x BN=64, BK=64, 4 waves (m-split),
// ONE barrier per K-tile. LDS 48KB -> 2 blocks/CU (grid 512 = 2/CU).
__global__ __launch_bounds__(256, 2)
void gemm_out(const u16* __restrict__ A, const u16* __restrict__ W,
              const float* __restrict__ bias, float* __restrict__ outf)
{
  __shared__ __align__(16) u16 Al[2][128 * 64];
  __shared__ __align__(16) u16 Bl[2][64 * 64];
  const int K = 1024, N = 1024;
  const int tid = threadIdx.x;
  const int w = tid >> 6, l = tid & 63;
  const int lg = l >> 4, lr = l & 15;
  const int tM = blockIdx.y * 128, tN = blockIdx.x * 64;

  f32x4 acc[2][4] = {};

  const int srow = l >> 3;
  const int scol = ((l & 7) ^ srow) << 3;
  const u16* asrc = A + (size_t)(tM + w * 32 + srow) * K + scol;
  const u16* bsrc = W + (size_t)(tN + w * 16 + srow) * K + scol;

  auto STG = [&](int buf, int k0) {
#pragma unroll
    for (int j = 0; j < 4; ++j)
      gload_lds16(asrc + (size_t)(j * 8) * K + k0, &Al[buf][(w * 32 + j * 8) * 64]);
#pragma unroll
    for (int j = 0; j < 2; ++j)
      gload_lds16(bsrc + (size_t)(j * 8) * K + k0, &Bl[buf][(w * 16 + j * 8) * 64]);
  };

  STG(0, 0);
  asm volatile("s_waitcnt vmcnt(0)" ::: "memory");
  SBAR();

  const int sw = lr & 7;

  for (int t = 0; t < 16; ++t) {
    const int cur = t & 1;
    if (t + 1 < 16) STG(cur ^ 1, (t + 1) * 64);

    bf16x8 af[2][2];
#pragma unroll
    for (int m = 0; m < 2; ++m)
#pragma unroll
      for (int kk = 0; kk < 2; ++kk)
        af[m][kk] = *(const bf16x8*)&Al[cur][(w * 32 + m * 16 + lr) * 64 +
                                            (((kk * 4 + lg) ^ sw) << 3)];
    __builtin_amdgcn_s_setprio(1);
#pragma unroll
    for (int n = 0; n < 4; ++n) {
      bf16x8 bw0 = *(const bf16x8*)&Bl[cur][(n * 16 + lr) * 64 + (((lg) ^ sw) << 3)];
      bf16x8 bw1 = *(const bf16x8*)&Bl[cur][(n * 16 + lr) * 64 + (((4 + lg) ^ sw) << 3)];
#pragma unroll
      for (int m = 0; m < 2; ++m) {
        acc[m][n] = __builtin_amdgcn_mfma_f32_16x16x32_bf16(af[m][0], bw0, acc[m][n], 0, 0, 0);
        acc[m][n] = __builtin_amdgcn_mfma_f32_16x16x32_bf16(af[m][1], bw1, acc[m][n], 0, 0, 0);
      }
    }
    __builtin_amdgcn_s_setprio(0);

    asm volatile("s_waitcnt vmcnt(0)" ::: "memory");
    SBAR();
  }

#pragma unroll
  for (int n = 0; n < 4; ++n) {
    const int col = tN + n * 16 + lr;
    const float bv = bias[col];
#pragma unroll
    for (int m = 0; m < 2; ++m)
#pragma unroll
      for (int r = 0; r < 4; ++r) {
        const int row = tM + w * 32 + m * 16 + lg * 4 + r;
        outf[(size_t)row * N + col] = acc[m][n][r] + bv;
      }
  }
}

// Flash attention (R11 structure, 49.0us, frozen): KVBLK=128 per barrier, two
// independent 64-kv sub-tiles A/B; 32x32x16 MFMA, in-register P via
// cvt_pk+permlane32_swap, zero-shift softmax. LDS 64KB -> 2 blocks/CU.
// Grid 512, bh in low 5 bits (XCD-local K/V).
__global__ __launch_bounds__(256, 2)
void attn_fwd(const u16* __restrict__ qb, const u16* __restrict__ kb,
              const u16* __restrict__ vtb, u16* __restrict__ ob)
{
  __shared__ __align__(16) u16 Kl[2][2][64 * 64];
  __shared__ __align__(16) u16 Vl[2][2][64 * 64];

  const int tid = threadIdx.x;
  const int w = tid >> 6, l = tid & 63;
  const int q32 = l & 31, hi = l >> 5;
  const int idx = blockIdx.x;
  const int bh = idx & 31, qt = idx >> 5;
  const int bb = bh >> 4, hh = bh & 15;
  const int q0 = qt * 128 + w * 32;

  bf16x8 qf[4];
#pragma unroll
  for (int ks = 0; ks < 4; ++ks)
    qf[ks] = *(const bf16x8*)&qb[((size_t)bh * S_ + q0 + q32) * HD_ + ks * 16 + hi * 8];

  const f32x16 z16 = {};
  f32x16 acc[2] = {z16, z16};
  float lrun = 0.f;

  const int srow = l >> 3;
  const int scol = ((l & 7) ^ srow) << 3;
  const u16* kbase = kb  + ((size_t)bh * S_  + w * 16 + srow) * HD_ + scol;
  const u16* vbase = vtb + ((size_t)bh * HD_ + w * 16 + srow) * S_  + scol;

  auto STAGE = [&](int buf, int t) {
#pragma unroll
    for (int s = 0; s < 2; ++s)
#pragma unroll
      for (int j = 0; j < 2; ++j) {
        gload_lds16(kbase + ((size_t)t * 128 + s * 64) * HD_ + j * 8 * HD_,
                    &Kl[buf][s][(w * 16 + j * 8) * 64]);
        gload_lds16(vbase + (size_t)t * 128 + s * 64 + j * 8 * S_,
                    &Vl[buf][s][(w * 16 + j * 8) * 64]);
      }
  };

  STAGE(0, 0);
  __syncthreads();

  const int sw = q32 & 7;

  auto SOFTMAX = [&](f32x16& st0, f32x16& st1, bf16x8* pa) {
#pragma unroll
    for (int kt = 0; kt < 2; ++kt) {
      const f32x16& stt = kt ? st1 : st0;
      float p[16];
#pragma unroll
      for (int r = 0; r < 16; ++r) p[r] = ex2(stt[r]);
#pragma unroll
      for (int g = 0; g < 4; ++g)
        lrun += (p[4 * g] + p[4 * g + 1]) + (p[4 * g + 2] + p[4 * g + 3]);
      u32 wk0[4], wk1[4];
#pragma unroll
      for (int g = 0; g < 4; ++g) {
        wk0[g] = cvtpk(p[4 * g], p[4 * g + 1]);
        wk1[g] = cvtpk(p[4 * g + 2], p[4 * g + 3]);
      }
#pragma unroll
      for (int k2 = 0; k2 < 2; ++k2) {
        u32 a0 = wk0[2 * k2], b0 = wk0[2 * k2 + 1];
        u32 a1 = wk1[2 * k2], b1 = wk1[2 * k2 + 1];
        asm volatile("v_permlane32_swap_b32 %0, %1" : "+v"(a0), "+v"(b0));
        asm volatile("v_permlane32_swap_b32 %0, %1" : "+v"(a1), "+v"(b1));
        uint4 wv = {a0, a1, b0, b1};
        pa[kt * 2 + k2] = __builtin_bit_cast(bf16x8, wv);
      }
    }
  };

  for (int t = 0; t < 16; ++t) {
    const int cur = t & 1;
    if (t + 1 < 16) STAGE(cur ^ 1, t + 1);

    f32x16 stA0 = z16, stA1 = z16, stB0 = z16, stB1 = z16;
    __builtin_amdgcn_s_setprio(1);
#pragma unroll
    for (int ks = 0; ks < 4; ++ks) {
      const int so = ((((ks << 1) | hi) ^ sw) << 3);
      const bf16x8 kfA0 = *(const bf16x8*)&Kl[cur][0][(q32) * 64 + so];
      const bf16x8 kfA1 = *(const bf16x8*)&Kl[cur][0][(32 + q32) * 64 + so];
      const bf16x8 kfB0 = *(const bf16x8*)&Kl[cur][1][(q32) * 64 + so];
      const bf16x8 kfB1 = *(const bf16x8*)&Kl[cur][1][(32 + q32) * 64 + so];
      stA0 = __builtin_amdgcn_mfma_f32_32x32x16_bf16(kfA0, qf[ks], stA0, 0, 0, 0);
      stA1 = __builtin_amdgcn_mfma_f32_32x32x16_bf16(kfA1, qf[ks], stA1, 0, 0, 0);
      stB0 = __builtin_amdgcn_mfma_f32_32x32x16_bf16(kfB0, qf[ks], stB0, 0, 0, 0);
      stB1 = __builtin_amdgcn_mfma_f32_32x32x16_bf16(kfB1, qf[ks], stB1, 0, 0, 0);
    }
    __builtin_amdgcn_s_setprio(0);

    bf16x8 pa[4];
    SOFTMAX(stA0, stA1, pa);
    __builtin_amdgcn_s_setprio(1);
#pragma unroll
    for (int dt = 0; dt < 2; ++dt)
#pragma unroll
      for (int ks = 0; ks < 4; ++ks) {
        const bf16x8 vf = *(const bf16x8*)&Vl[cur][0][(dt * 32 + q32) * 64 + ((((ks << 1) | hi) ^ sw) << 3)];
        acc[dt] = __builtin_amdgcn_mfma_f32_32x32x16_bf16(vf, pa[ks], acc[dt], 0, 0, 0);
      }
    __builtin_amdgcn_s_setprio(0);

    SOFTMAX(stB0, stB1, pa);
    __builtin_amdgcn_s_setprio(1);
#pragma unroll
    for (int dt = 0; dt < 2; ++dt)
#pragma unroll
      for (int ks = 0; ks < 4; ++ks) {
        const bf16x8 vf = *(const bf16x8*)&Vl[cur][1][(dt * 32 + q32) * 64 + ((((ks << 1) | hi) ^ sw) << 3)];
        acc[dt] = __builtin_amdgcn_mfma_f32_32x32x16_bf16(vf, pa[ks], acc[dt], 0, 0, 0);
      }
    __builtin_amdgcn_s_setprio(0);

    __syncthreads();
  }

  lrun += __shfl_xor(lrun, 32);
  const float linv = 1.f / lrun;
  const size_t orow = ((size_t)(bb * S_ + q0 + q32)) * H_ + hh * HD_;
#pragma unroll
  for (int dt = 0; dt < 2; ++dt)
#pragma unroll
    for (int g = 0; g < 4; ++g) {
      const u32 o0 = cvtpk(acc[dt][4 * g] * linv, acc[dt][4 * g + 1] * linv);
      const u32 o1 = cvtpk(acc[dt][4 * g + 2] * linv, acc[dt][4 * g + 3] * linv);
      uint2 ov; ov.x = o0; ov.y = o1;
      *(uint2*)&ob[orow + dt * 32 + g * 8 + hi * 4] = ov;
    }
}

extern "C" void kernel_launch(void* const* d_in, const int* in_sizes, int n_in,
                              void* d_out, int out_size, void* d_ws, size_t ws_size,
                              hipStream_t stream) {
  const float* x     = (const float*)d_in[0];
  const float* qkv_w = (const float*)d_in[1];
  const float* qkv_b = (const float*)d_in[2];
  const float* out_w = (const float*)d_in[3];
  const float* out_b = (const float*)d_in[4];

  char* ws = (char*)d_ws;
  u16* xb    = (u16*)(ws);              // 8 MB
  u16* wqkvb = (u16*)(ws + 8388608);    // 6 MB
  u16* wob   = (u16*)(ws + 14680064);   // 2 MB
  u16* qb    = (u16*)(ws + 16777216);   // 8 MB
  u16* kb    = (u16*)(ws + 25165824);   // 8 MB
  u16* vtb   = (u16*)(ws + 33554432);   // 8 MB (V transposed [b,h,d,s], written by gemm_qkv)
  u16* ob    = (u16*)(ws + 41943040);   // 8 MB -> 48 MB total

  cvt_all<<<8192, 256, 0, stream>>>(x, qkv_w, out_w, xb, wqkvb, wob);

  gemm_qkv<<<dim3(16, 32), 512, 0, stream>>>(xb, wqkvb, qkv_b, qb, kb, vtb);
  attn_fwd<<<512, 256, 0, stream>>>(qb, kb, vtb, ob);
  gemm_out<<<dim3(16, 32), 256, 0, stream>>>(ob, wob, out_b, (float*)d_out);
}

// Round 18
// 98.053 us; speedup vs baseline: 1.0302x; 1.0302x over previous
//
#include <hip/hip_runtime.h>
#include <stdint.h>

typedef __bf16 bf16x8 __attribute__((ext_vector_type(8)));
typedef float  f32x4  __attribute__((ext_vector_type(4)));
typedef float  f32x16 __attribute__((ext_vector_type(16)));
typedef unsigned short u16;
typedef unsigned int   u32;

#define B_  2
#define S_  2048
#define H_  1024
#define NH_ 16
#define HD_ 64
#define QSCL 0.18033688011112042f  /* 0.125 * log2(e) */

__device__ __forceinline__ u16 f2bf(float f) {
  u32 u = __builtin_bit_cast(u32, f);
  return (u16)((u + 0x7FFFu + ((u >> 16) & 1u)) >> 16);
}
__device__ __forceinline__ float ex2(float x) { return __builtin_amdgcn_exp2f(x); }
__device__ __forceinline__ u32 cvtpk(float lo, float hi) {
  u32 r; asm("v_cvt_pk_bf16_f32 %0, %1, %2" : "=v"(r) : "v"(lo), "v"(hi)); return r;
}
__device__ __forceinline__ void gload_lds16(const u16* g, u16* lds) {
  __builtin_amdgcn_global_load_lds(
      (__attribute__((address_space(1))) void*)(void*)g,
      (__attribute__((address_space(3))) void*)lds, 16, 0, 0);
}
#define SBAR() asm volatile("s_barrier" ::: "memory")

__global__ void cvt_all(const float* __restrict__ a, const float* __restrict__ b,
                        const float* __restrict__ c, u16* __restrict__ oa,
                        u16* __restrict__ ob, u16* __restrict__ oc) {
  int i = blockIdx.x * 256 + threadIdx.x;
  const float4* src; ushort4* dst; int j;
  if (i < 1048576)      { src = (const float4*)a; dst = (ushort4*)oa; j = i; }
  else if (i < 1835008) { src = (const float4*)b; dst = (ushort4*)ob; j = i - 1048576; }
  else                  { src = (const float4*)c; dst = (ushort4*)oc; j = i - 1835008; }
  const float4 v = src[j];
  ushort4 o;
  o.x = f2bf(v.x); o.y = f2bf(v.y); o.z = f2bf(v.z); o.w = f2bf(v.w);
  dst[j] = o;
}

// QKV GEMM (R16 form, proven 98.2us total): R13 structure + FUSED V-TRANSPOSE
// epilogue. BM=128 x BN=192, BK=64, 4 waves, ONE barrier per K-tile, LDS 80KB
// -> 2 blocks/CU (grid 512 = 2/CU). q,k stored [b,h,s,d] (q pre-scaled by
// QSCL); v stored DIRECTLY transposed [b,h,d,s] via block-local LDS transpose
// (Vt aliases dead staging LDS after the final barrier).
__global__ __launch_bounds__(256, 2)
void gemm_qkv(const u16* __restrict__ A, const u16* __restrict__ W,
              const float* __restrict__ bias,
              u16* __restrict__ qb, u16* __restrict__ kb, u16* __restrict__ vtb)
{
  __shared__ __align__(16) u16 smem[40960];   // 80 KB: Al[2]@0/8192, Bl[2]@16384/28672
  u16* const Vt = smem;                        // [192][136] alias, used post-loop
  const int K = 1024;
  const int tid = threadIdx.x;
  const int w = tid >> 6, l = tid & 63;
  const int lg = l >> 4, lr = l & 15;
  const int wm = w >> 1, wn = w & 1;
  const int tM = blockIdx.y * 128, tN = blockIdx.x * 192;

  f32x4 acc[4][6] = {};

  const int srow = l >> 3;
  const int scol = ((l & 7) ^ srow) << 3;
  const u16* asrc = A + (size_t)(tM + w * 32 + srow) * K + scol;
  const u16* bsrc = W + (size_t)(tN + w * 48 + srow) * K + scol;

  auto STG = [&](int buf, int k0) {
#pragma unroll
    for (int j = 0; j < 4; ++j)
      gload_lds16(asrc + (size_t)(j * 8) * K + k0, &smem[buf * 8192 + (w * 32 + j * 8) * 64]);
#pragma unroll
    for (int j = 0; j < 6; ++j)
      gload_lds16(bsrc + (size_t)(j * 8) * K + k0, &smem[16384 + buf * 12288 + (w * 48 + j * 8) * 64]);
  };

  STG(0, 0);
  asm volatile("s_waitcnt vmcnt(0)" ::: "memory");
  SBAR();

  const int sw = lr & 7;

  for (int t = 0; t < 16; ++t) {
    const int cur = t & 1;
    if (t + 1 < 16) STG(cur ^ 1, (t + 1) * 64);

    bf16x8 af[4][2];
#pragma unroll
    for (int m = 0; m < 4; ++m)
#pragma unroll
      for (int kk = 0; kk < 2; ++kk)
        af[m][kk] = *(const bf16x8*)&smem[cur * 8192 + (wm * 64 + m * 16 + lr) * 64 +
                                          (((kk * 4 + lg) ^ sw) << 3)];
    __builtin_amdgcn_s_setprio(1);
#pragma unroll
    for (int n = 0; n < 6; ++n) {
      bf16x8 bw0 = *(const bf16x8*)&smem[16384 + cur * 12288 + (wn * 96 + n * 16 + lr) * 64 + (((lg) ^ sw) << 3)];
      bf16x8 bw1 = *(const bf16x8*)&smem[16384 + cur * 12288 + (wn * 96 + n * 16 + lr) * 64 + (((4 + lg) ^ sw) << 3)];
#pragma unroll
      for (int m = 0; m < 4; ++m) {
        acc[m][n] = __builtin_amdgcn_mfma_f32_16x16x32_bf16(af[m][0], bw0, acc[m][n], 0, 0, 0);
        acc[m][n] = __builtin_amdgcn_mfma_f32_16x16x32_bf16(af[m][1], bw1, acc[m][n], 0, 0, 0);
      }
    }
    __builtin_amdgcn_s_setprio(0);

    asm volatile("s_waitcnt vmcnt(0)" ::: "memory");
    SBAR();
  }

  // ---- epilogue ----
  const int bb = tM >> 11, ssb = tM & 2047;
#pragma unroll
  for (int n = 0; n < 6; ++n) {
    const int cl = wn * 96 + n * 16 + lr;       // col within block
    const int col = tN + cl;
    const float bv = bias[col];
    const int t3 = col >> 10, rem = col & 1023;
    const int hh = rem >> 6, dd = rem & 63;
    if (t3 < 2) {
      const float sc = (t3 == 0) ? QSCL : 1.f;
      u16* dst = (t3 == 0) ? qb : kb;
#pragma unroll
      for (int m = 0; m < 4; ++m)
#pragma unroll
        for (int r = 0; r < 4; ++r) {
          const int row = tM + wm * 64 + m * 16 + lg * 4 + r;
          dst[((size_t)(bb * NH_ + hh) * S_ + (row & 2047)) * HD_ + dd] = f2bf((acc[m][n][r] + bv) * sc);
        }
    } else {
      // v: pack 4 consecutive rows -> Vt[cl][row_local], transposed store later
#pragma unroll
      for (int m = 0; m < 4; ++m) {
        ushort4 pk;
        pk.x = f2bf(acc[m][n][0] + bv);
        pk.y = f2bf(acc[m][n][1] + bv);
        pk.z = f2bf(acc[m][n][2] + bv);
        pk.w = f2bf(acc[m][n][3] + bv);
        *(ushort4*)&Vt[cl * 136 + wm * 64 + m * 16 + lg * 4] = pk;
      }
    }
  }

  if (tN >= 1920) {                       // block has v columns (bx >= 10)
    __syncthreads();                      // uniform condition -> legal
    const int cl0 = (tN < 2048) ? (2048 - tN) : 0;
    const int nch = (192 - cl0) * 16;     // (col, 8-ss-chunk) pairs
    for (int c = tid; c < nch; c += 256) {
      const int cv = cl0 + (c >> 4), ch = c & 15;
      const int rem = (tN + cv) & 1023;
      const int hh2 = rem >> 6, dd2 = rem & 63;
      const uint4 v = *(const uint4*)&Vt[cv * 136 + ch * 8];
      *(uint4*)&vtb[((size_t)(bb * NH_ + hh2) * HD_ + dd2) * S_ + ssb + ch * 8] = v;
    }
  }
}

// Out-proj (R14 structure, frozen): BM=128 x BN=64, BK=64, 4 waves (m-split),
// ONE barrier per K-tile. LDS 48KB -> 2 blocks/CU (grid 512 = 2/CU).
__global__ __launch_bounds__(256, 2)
void gemm_out(const u16* __restrict__ A, const u16* __restrict__ W,
              const float* __restrict__ bias, float* __restrict__ outf)
{
  __shared__ __align__(16) u16 Al[2][128 * 64];
  __shared__ __align__(16) u16 Bl[2][64 * 64];
  const int K = 1024, N = 1024;
  const int tid = threadIdx.x;
  const int w = tid >> 6, l = tid & 63;
  const int lg = l >> 4, lr = l & 15;
  const int tM = blockIdx.y * 128, tN = blockIdx.x * 64;

  f32x4 acc[2][4] = {};

  const int srow = l >> 3;
  const int scol = ((l & 7) ^ srow) << 3;
  const u16* asrc = A + (size_t)(tM + w * 32 + srow) * K + scol;
  const u16* bsrc = W + (size_t)(tN + w * 16 + srow) * K + scol;

  auto STG = [&](int buf, int k0) {
#pragma unroll
    for (int j = 0; j < 4; ++j)
      gload_lds16(asrc + (size_t)(j * 8) * K + k0, &Al[buf][(w * 32 + j * 8) * 64]);
#pragma unroll
    for (int j = 0; j < 2; ++j)
      gload_lds16(bsrc + (size_t)(j * 8) * K + k0, &Bl[buf][(w * 16 + j * 8) * 64]);
  };

  STG(0, 0);
  asm volatile("s_waitcnt vmcnt(0)" ::: "memory");
  SBAR();

  const int sw = lr & 7;

  for (int t = 0; t < 16; ++t) {
    const int cur = t & 1;
    if (t + 1 < 16) STG(cur ^ 1, (t + 1) * 64);

    bf16x8 af[2][2];
#pragma unroll
    for (int m = 0; m < 2; ++m)
#pragma unroll
      for (int kk = 0; kk < 2; ++kk)
        af[m][kk] = *(const bf16x8*)&Al[cur][(w * 32 + m * 16 + lr) * 64 +
                                            (((kk * 4 + lg) ^ sw) << 3)];
    __builtin_amdgcn_s_setprio(1);
#pragma unroll
    for (int n = 0; n < 4; ++n) {
      bf16x8 bw0 = *(const bf16x8*)&Bl[cur][(n * 16 + lr) * 64 + (((lg) ^ sw) << 3)];
      bf16x8 bw1 = *(const bf16x8*)&Bl[cur][(n * 16 + lr) * 64 + (((4 + lg) ^ sw) << 3)];
#pragma unroll
      for (int m = 0; m < 2; ++m) {
        acc[m][n] = __builtin_amdgcn_mfma_f32_16x16x32_bf16(af[m][0], bw0, acc[m][n], 0, 0, 0);
        acc[m][n] = __builtin_amdgcn_mfma_f32_16x16x32_bf16(af[m][1], bw1, acc[m][n], 0, 0, 0);
      }
    }
    __builtin_amdgcn_s_setprio(0);

    asm volatile("s_waitcnt vmcnt(0)" ::: "memory");
    SBAR();
  }

#pragma unroll
  for (int n = 0; n < 4; ++n) {
    const int col = tN + n * 16 + lr;
    const float bv = bias[col];
#pragma unroll
    for (int m = 0; m < 2; ++m)
#pragma unroll
      for (int r = 0; r < 4; ++r) {
        const int row = tM + w * 32 + m * 16 + lg * 4 + r;
        outf[(size_t)row * N + col] = acc[m][n][r] + bv;
      }
  }
}

// Flash attention (R11 structure, 49.0us, frozen): KVBLK=128 per barrier, two
// independent 64-kv sub-tiles A/B; 32x32x16 MFMA, in-register P via
// cvt_pk+permlane32_swap, zero-shift softmax. LDS 64KB -> 2 blocks/CU.
// Grid 512, bh in low 5 bits (XCD-local K/V).
__global__ __launch_bounds__(256, 2)
void attn_fwd(const u16* __restrict__ qb, const u16* __restrict__ kb,
              const u16* __restrict__ vtb, u16* __restrict__ ob)
{
  __shared__ __align__(16) u16 Kl[2][2][64 * 64];
  __shared__ __align__(16) u16 Vl[2][2][64 * 64];

  const int tid = threadIdx.x;
  const int w = tid >> 6, l = tid & 63;
  const int q32 = l & 31, hi = l >> 5;
  const int idx = blockIdx.x;
  const int bh = idx & 31, qt = idx >> 5;
  const int bb = bh >> 4, hh = bh & 15;
  const int q0 = qt * 128 + w * 32;

  bf16x8 qf[4];
#pragma unroll
  for (int ks = 0; ks < 4; ++ks)
    qf[ks] = *(const bf16x8*)&qb[((size_t)bh * S_ + q0 + q32) * HD_ + ks * 16 + hi * 8];

  const f32x16 z16 = {};
  f32x16 acc[2] = {z16, z16};
  float lrun = 0.f;

  const int srow = l >> 3;
  const int scol = ((l & 7) ^ srow) << 3;
  const u16* kbase = kb  + ((size_t)bh * S_  + w * 16 + srow) * HD_ + scol;
  const u16* vbase = vtb + ((size_t)bh * HD_ + w * 16 + srow) * S_  + scol;

  auto STAGE = [&](int buf, int t) {
#pragma unroll
    for (int s = 0; s < 2; ++s)
#pragma unroll
      for (int j = 0; j < 2; ++j) {
        gload_lds16(kbase + ((size_t)t * 128 + s * 64) * HD_ + j * 8 * HD_,
                    &Kl[buf][s][(w * 16 + j * 8) * 64]);
        gload_lds16(vbase + (size_t)t * 128 + s * 64 + j * 8 * S_,
                    &Vl[buf][s][(w * 16 + j * 8) * 64]);
      }
  };

  STAGE(0, 0);
  __syncthreads();

  const int sw = q32 & 7;

  auto SOFTMAX = [&](f32x16& st0, f32x16& st1, bf16x8* pa) {
#pragma unroll
    for (int kt = 0; kt < 2; ++kt) {
      const f32x16& stt = kt ? st1 : st0;
      float p[16];
#pragma unroll
      for (int r = 0; r < 16; ++r) p[r] = ex2(stt[r]);
#pragma unroll
      for (int g = 0; g < 4; ++g)
        lrun += (p[4 * g] + p[4 * g + 1]) + (p[4 * g + 2] + p[4 * g + 3]);
      u32 wk0[4], wk1[4];
#pragma unroll
      for (int g = 0; g < 4; ++g) {
        wk0[g] = cvtpk(p[4 * g], p[4 * g + 1]);
        wk1[g] = cvtpk(p[4 * g + 2], p[4 * g + 3]);
      }
#pragma unroll
      for (int k2 = 0; k2 < 2; ++k2) {
        u32 a0 = wk0[2 * k2], b0 = wk0[2 * k2 + 1];
        u32 a1 = wk1[2 * k2], b1 = wk1[2 * k2 + 1];
        asm volatile("v_permlane32_swap_b32 %0, %1" : "+v"(a0), "+v"(b0));
        asm volatile("v_permlane32_swap_b32 %0, %1" : "+v"(a1), "+v"(b1));
        uint4 wv = {a0, a1, b0, b1};
        pa[kt * 2 + k2] = __builtin_bit_cast(bf16x8, wv);
      }
    }
  };

  for (int t = 0; t < 16; ++t) {
    const int cur = t & 1;
    if (t + 1 < 16) STAGE(cur ^ 1, t + 1);

    f32x16 stA0 = z16, stA1 = z16, stB0 = z16, stB1 = z16;
    __builtin_amdgcn_s_setprio(1);
#pragma unroll
    for (int ks = 0; ks < 4; ++ks) {
      const int so = ((((ks << 1) | hi) ^ sw) << 3);
      const bf16x8 kfA0 = *(const bf16x8*)&Kl[cur][0][(q32) * 64 + so];
      const bf16x8 kfA1 = *(const bf16x8*)&Kl[cur][0][(32 + q32) * 64 + so];
      const bf16x8 kfB0 = *(const bf16x8*)&Kl[cur][1][(q32) * 64 + so];
      const bf16x8 kfB1 = *(const bf16x8*)&Kl[cur][1][(32 + q32) * 64 + so];
      stA0 = __builtin_amdgcn_mfma_f32_32x32x16_bf16(kfA0, qf[ks], stA0, 0, 0, 0);
      stA1 = __builtin_amdgcn_mfma_f32_32x32x16_bf16(kfA1, qf[ks], stA1, 0, 0, 0);
      stB0 = __builtin_amdgcn_mfma_f32_32x32x16_bf16(kfB0, qf[ks], stB0, 0, 0, 0);
      stB1 = __builtin_amdgcn_mfma_f32_32x32x16_bf16(kfB1, qf[ks], stB1, 0, 0, 0);
    }
    __builtin_amdgcn_s_setprio(0);

    bf16x8 pa[4];
    SOFTMAX(stA0, stA1, pa);
    __builtin_amdgcn_s_setprio(1);
#pragma unroll
    for (int dt = 0; dt < 2; ++dt)
#pragma unroll
      for (int ks = 0; ks < 4; ++ks) {
        const bf16x8 vf = *(const bf16x8*)&Vl[cur][0][(dt * 32 + q32) * 64 + ((((ks << 1) | hi) ^ sw) << 3)];
        acc[dt] = __builtin_amdgcn_mfma_f32_32x32x16_bf16(vf, pa[ks], acc[dt], 0, 0, 0);
      }
    __builtin_amdgcn_s_setprio(0);

    SOFTMAX(stB0, stB1, pa);
    __builtin_amdgcn_s_setprio(1);
#pragma unroll
    for (int dt = 0; dt < 2; ++dt)
#pragma unroll
      for (int ks = 0; ks < 4; ++ks) {
        const bf16x8 vf = *(const bf16x8*)&Vl[cur][1][(dt * 32 + q32) * 64 + ((((ks << 1) | hi) ^ sw) << 3)];
        acc[dt] = __builtin_amdgcn_mfma_f32_32x32x16_bf16(vf, pa[ks], acc[dt], 0, 0, 0);
      }
    __builtin_amdgcn_s_setprio(0);

    __syncthreads();
  }

  lrun += __shfl_xor(lrun, 32);
  const float linv = 1.f / lrun;
  const size_t orow = ((size_t)(bb * S_ + q0 + q32)) * H_ + hh * HD_;
#pragma unroll
  for (int dt = 0; dt < 2; ++dt)
#pragma unroll
    for (int g = 0; g < 4; ++g) {
      const u32 o0 = cvtpk(acc[dt][4 * g] * linv, acc[dt][4 * g + 1] * linv);
      const u32 o1 = cvtpk(acc[dt][4 * g + 2] * linv, acc[dt][4 * g + 3] * linv);
      uint2 ov; ov.x = o0; ov.y = o1;
      *(uint2*)&ob[orow + dt * 32 + g * 8 + hi * 4] = ov;
    }
}

extern "C" void kernel_launch(void* const* d_in, const int* in_sizes, int n_in,
                              void* d_out, int out_size, void* d_ws, size_t ws_size,
                              hipStream_t stream) {
  const float* x     = (const float*)d_in[0];
  const float* qkv_w = (const float*)d_in[1];
  const float* qkv_b = (const float*)d_in[2];
  const float* out_w = (const float*)d_in[3];
  const float* out_b = (const float*)d_in[4];

  char* ws = (char*)d_ws;
  u16* xb    = (u16*)(ws);              // 8 MB
  u16* wqkvb = (u16*)(ws + 8388608);    // 6 MB
  u16* wob   = (u16*)(ws + 14680064);   // 2 MB
  u16* qb    = (u16*)(ws + 16777216);   // 8 MB
  u16* kb    = (u16*)(ws + 25165824);   // 8 MB
  u16* vtb   = (u16*)(ws + 33554432);   // 8 MB (V transposed [b,h,d,s], written by gemm_qkv)
  u16* ob    = (u16*)(ws + 41943040);   // 8 MB -> 48 MB total

  cvt_all<<<8192, 256, 0, stream>>>(x, qkv_w, out_w, xb, wqkvb, wob);

  gemm_qkv<<<dim3(16, 32), 256, 0, stream>>>(xb, wqkvb, qkv_b, qb, kb, vtb);
  attn_fwd<<<512, 256, 0, stream>>>(qb, kb, vtb, ob);
  gemm_out<<<dim3(16, 32), 256, 0, stream>>>(ob, wob, out_b, (float*)d_out);
}

// Round 19
// 97.709 us; speedup vs baseline: 1.0338x; 1.0035x over previous
//
#include <hip/hip_runtime.h>
#include <stdint.h>

typedef __bf16 bf16x8 __attribute__((ext_vector_type(8)));
typedef float  f32x4  __attribute__((ext_vector_type(4)));
typedef float  f32x16 __attribute__((ext_vector_type(16)));
typedef unsigned short u16;
typedef unsigned int   u32;

#define B_  2
#define S_  2048
#define H_  1024
#define NH_ 16
#define HD_ 64
#define QSCL 0.18033688011112042f  /* 0.125 * log2(e) */

__device__ __forceinline__ u16 f2bf(float f) {
  u32 u = __builtin_bit_cast(u32, f);
  return (u16)((u + 0x7FFFu + ((u >> 16) & 1u)) >> 16);
}
__device__ __forceinline__ float ex2(float x) { return __builtin_amdgcn_exp2f(x); }
__device__ __forceinline__ u32 cvtpk(float lo, float hi) {
  u32 r; asm("v_cvt_pk_bf16_f32 %0, %1, %2" : "=v"(r) : "v"(lo), "v"(hi)); return r;
}
__device__ __forceinline__ void gload_lds16(const u16* g, u16* lds) {
  __builtin_amdgcn_global_load_lds(
      (__attribute__((address_space(1))) void*)(void*)g,
      (__attribute__((address_space(3))) void*)lds, 16, 0, 0);
}
#define SBAR() asm volatile("s_barrier" ::: "memory")

__global__ void cvt_all(const float* __restrict__ a, const float* __restrict__ b,
                        const float* __restrict__ c, u16* __restrict__ oa,
                        u16* __restrict__ ob, u16* __restrict__ oc) {
  int i = blockIdx.x * 256 + threadIdx.x;
  const float4* src; ushort4* dst; int j;
  if (i < 1048576)      { src = (const float4*)a; dst = (ushort4*)oa; j = i; }
  else if (i < 1835008) { src = (const float4*)b; dst = (ushort4*)ob; j = i - 1048576; }
  else                  { src = (const float4*)c; dst = (ushort4*)oc; j = i - 1835008; }
  const float4 v = src[j];
  ushort4 o;
  o.x = f2bf(v.x); o.y = f2bf(v.y); o.z = f2bf(v.z); o.w = f2bf(v.w);
  dst[j] = o;
}

// QKV GEMM (R16 form) + XCD-aware block swizzle (T1): 1D grid 512; linear
// wgid round-robins XCDs, so swz = (wgid&7)*64 + wgid>>3 gives XCD k the
// contiguous swz range [k*64,(k+1)*64) = 4 complete by-groups -> each 256KB
// A-panel lands in exactly ONE XCD's L2 and is hit by all 16 bx blocks.
// BM=128 x BN=192, BK=64, 4 waves, ONE barrier per K-tile, LDS 80KB ->
// 2 blocks/CU. Fused V-transpose epilogue; q pre-scaled by QSCL.
__global__ __launch_bounds__(256, 2)
void gemm_qkv(const u16* __restrict__ A, const u16* __restrict__ W,
              const float* __restrict__ bias,
              u16* __restrict__ qb, u16* __restrict__ kb, u16* __restrict__ vtb)
{
  __shared__ __align__(16) u16 smem[40960];   // 80 KB: Al[2]@0/8192, Bl[2]@16384/28672
  u16* const Vt = smem;                        // [192][136] alias, used post-loop
  const int K = 1024;
  const int tid = threadIdx.x;
  const int w = tid >> 6, l = tid & 63;
  const int lg = l >> 4, lr = l & 15;
  const int wm = w >> 1, wn = w & 1;
  const int wgid = blockIdx.x;
  const int swz = (wgid & 7) * 64 + (wgid >> 3);   // bijective (512 % 8 == 0)
  const int tM = (swz >> 4) * 128, tN = (swz & 15) * 192;

  f32x4 acc[4][6] = {};

  const int srow = l >> 3;
  const int scol = ((l & 7) ^ srow) << 3;
  const u16* asrc = A + (size_t)(tM + w * 32 + srow) * K + scol;
  const u16* bsrc = W + (size_t)(tN + w * 48 + srow) * K + scol;

  auto STG = [&](int buf, int k0) {
#pragma unroll
    for (int j = 0; j < 4; ++j)
      gload_lds16(asrc + (size_t)(j * 8) * K + k0, &smem[buf * 8192 + (w * 32 + j * 8) * 64]);
#pragma unroll
    for (int j = 0; j < 6; ++j)
      gload_lds16(bsrc + (size_t)(j * 8) * K + k0, &smem[16384 + buf * 12288 + (w * 48 + j * 8) * 64]);
  };

  STG(0, 0);
  asm volatile("s_waitcnt vmcnt(0)" ::: "memory");
  SBAR();

  const int sw = lr & 7;

  for (int t = 0; t < 16; ++t) {
    const int cur = t & 1;
    if (t + 1 < 16) STG(cur ^ 1, (t + 1) * 64);

    bf16x8 af[4][2];
#pragma unroll
    for (int m = 0; m < 4; ++m)
#pragma unroll
      for (int kk = 0; kk < 2; ++kk)
        af[m][kk] = *(const bf16x8*)&smem[cur * 8192 + (wm * 64 + m * 16 + lr) * 64 +
                                          (((kk * 4 + lg) ^ sw) << 3)];
    __builtin_amdgcn_s_setprio(1);
#pragma unroll
    for (int n = 0; n < 6; ++n) {
      bf16x8 bw0 = *(const bf16x8*)&smem[16384 + cur * 12288 + (wn * 96 + n * 16 + lr) * 64 + (((lg) ^ sw) << 3)];
      bf16x8 bw1 = *(const bf16x8*)&smem[16384 + cur * 12288 + (wn * 96 + n * 16 + lr) * 64 + (((4 + lg) ^ sw) << 3)];
#pragma unroll
      for (int m = 0; m < 4; ++m) {
        acc[m][n] = __builtin_amdgcn_mfma_f32_16x16x32_bf16(af[m][0], bw0, acc[m][n], 0, 0, 0);
        acc[m][n] = __builtin_amdgcn_mfma_f32_16x16x32_bf16(af[m][1], bw1, acc[m][n], 0, 0, 0);
      }
    }
    __builtin_amdgcn_s_setprio(0);

    asm volatile("s_waitcnt vmcnt(0)" ::: "memory");
    SBAR();
  }

  // ---- epilogue ----
  const int bb = tM >> 11, ssb = tM & 2047;
#pragma unroll
  for (int n = 0; n < 6; ++n) {
    const int cl = wn * 96 + n * 16 + lr;       // col within block
    const int col = tN + cl;
    const float bv = bias[col];
    const int t3 = col >> 10, rem = col & 1023;
    const int hh = rem >> 6, dd = rem & 63;
    if (t3 < 2) {
      const float sc = (t3 == 0) ? QSCL : 1.f;
      u16* dst = (t3 == 0) ? qb : kb;
#pragma unroll
      for (int m = 0; m < 4; ++m)
#pragma unroll
        for (int r = 0; r < 4; ++r) {
          const int row = tM + wm * 64 + m * 16 + lg * 4 + r;
          dst[((size_t)(bb * NH_ + hh) * S_ + (row & 2047)) * HD_ + dd] = f2bf((acc[m][n][r] + bv) * sc);
        }
    } else {
      // v: pack 4 consecutive rows -> Vt[cl][row_local], transposed store later
#pragma unroll
      for (int m = 0; m < 4; ++m) {
        ushort4 pk;
        pk.x = f2bf(acc[m][n][0] + bv);
        pk.y = f2bf(acc[m][n][1] + bv);
        pk.z = f2bf(acc[m][n][2] + bv);
        pk.w = f2bf(acc[m][n][3] + bv);
        *(ushort4*)&Vt[cl * 136 + wm * 64 + m * 16 + lg * 4] = pk;
      }
    }
  }

  if (tN >= 1920) {                       // block has v columns
    __syncthreads();                      // uniform condition -> legal
    const int cl0 = (tN < 2048) ? (2048 - tN) : 0;
    const int nch = (192 - cl0) * 16;     // (col, 8-ss-chunk) pairs
    for (int c = tid; c < nch; c += 256) {
      const int cv = cl0 + (c >> 4), ch = c & 15;
      const int rem = (tN + cv) & 1023;
      const int hh2 = rem >> 6, dd2 = rem & 63;
      const uint4 v = *(const uint4*)&Vt[cv * 136 + ch * 8];
      *(uint4*)&vtb[((size_t)(bb * NH_ + hh2) * HD_ + dd2) * S_ + ssb + ch * 8] = v;
    }
  }
}

// Out-proj (R14 structure + XCD swizzle): BM=128 x BN=64, BK=64, 4 waves,
// ONE barrier per K-tile. LDS 48KB -> 2 blocks/CU. 1D grid 512, same swz map.
__global__ __launch_bounds__(256, 2)
void gemm_out(const u16* __restrict__ A, const u16* __restrict__ W,
              const float* __restrict__ bias, float* __restrict__ outf)
{
  __shared__ __align__(16) u16 Al[2][128 * 64];
  __shared__ __align__(16) u16 Bl[2][64 * 64];
  const int K = 1024, N = 1024;
  const int tid = threadIdx.x;
  const int w = tid >> 6, l = tid & 63;
  const int lg = l >> 4, lr = l & 15;
  const int wgid = blockIdx.x;
  const int swz = (wgid & 7) * 64 + (wgid >> 3);
  const int tM = (swz >> 4) * 128, tN = (swz & 15) * 64;

  f32x4 acc[2][4] = {};

  const int srow = l >> 3;
  const int scol = ((l & 7) ^ srow) << 3;
  const u16* asrc = A + (size_t)(tM + w * 32 + srow) * K + scol;
  const u16* bsrc = W + (size_t)(tN + w * 16 + srow) * K + scol;

  auto STG = [&](int buf, int k0) {
#pragma unroll
    for (int j = 0; j < 4; ++j)
      gload_lds16(asrc + (size_t)(j * 8) * K + k0, &Al[buf][(w * 32 + j * 8) * 64]);
#pragma unroll
    for (int j = 0; j < 2; ++j)
      gload_lds16(bsrc + (size_t)(j * 8) * K + k0, &Bl[buf][(w * 16 + j * 8) * 64]);
  };

  STG(0, 0);
  asm volatile("s_waitcnt vmcnt(0)" ::: "memory");
  SBAR();

  const int sw = lr & 7;

  for (int t = 0; t < 16; ++t) {
    const int cur = t & 1;
    if (t + 1 < 16) STG(cur ^ 1, (t + 1) * 64);

    bf16x8 af[2][2];
#pragma unroll
    for (int m = 0; m < 2; ++m)
#pragma unroll
      for (int kk = 0; kk < 2; ++kk)
        af[m][kk] = *(const bf16x8*)&Al[cur][(w * 32 + m * 16 + lr) * 64 +
                                            (((kk * 4 + lg) ^ sw) << 3)];
    __builtin_amdgcn_s_setprio(1);
#pragma unroll
    for (int n = 0; n < 4; ++n) {
      bf16x8 bw0 = *(const bf16x8*)&Bl[cur][(n * 16 + lr) * 64 + (((lg) ^ sw) << 3)];
      bf16x8 bw1 = *(const bf16x8*)&Bl[cur][(n * 16 + lr) * 64 + (((4 + lg) ^ sw) << 3)];
#pragma unroll
      for (int m = 0; m < 2; ++m) {
        acc[m][n] = __builtin_amdgcn_mfma_f32_16x16x32_bf16(af[m][0], bw0, acc[m][n], 0, 0, 0);
        acc[m][n] = __builtin_amdgcn_mfma_f32_16x16x32_bf16(af[m][1], bw1, acc[m][n], 0, 0, 0);
      }
    }
    __builtin_amdgcn_s_setprio(0);

    asm volatile("s_waitcnt vmcnt(0)" ::: "memory");
    SBAR();
  }

#pragma unroll
  for (int n = 0; n < 4; ++n) {
    const int col = tN + n * 16 + lr;
    const float bv = bias[col];
#pragma unroll
    for (int m = 0; m < 2; ++m)
#pragma unroll
      for (int r = 0; r < 4; ++r) {
        const int row = tM + w * 32 + m * 16 + lg * 4 + r;
        outf[(size_t)row * N + col] = acc[m][n][r] + bv;
      }
  }
}

// Flash attention (R11 structure, 49.0us, frozen): KVBLK=128 per barrier, two
// independent 64-kv sub-tiles A/B; 32x32x16 MFMA, in-register P via
// cvt_pk+permlane32_swap, zero-shift softmax. LDS 64KB -> 2 blocks/CU.
// Grid 512, bh in low 5 bits (XCD-local K/V).
__global__ __launch_bounds__(256, 2)
void attn_fwd(const u16* __restrict__ qb, const u16* __restrict__ kb,
              const u16* __restrict__ vtb, u16* __restrict__ ob)
{
  __shared__ __align__(16) u16 Kl[2][2][64 * 64];
  __shared__ __align__(16) u16 Vl[2][2][64 * 64];

  const int tid = threadIdx.x;
  const int w = tid >> 6, l = tid & 63;
  const int q32 = l & 31, hi = l >> 5;
  const int idx = blockIdx.x;
  const int bh = idx & 31, qt = idx >> 5;
  const int bb = bh >> 4, hh = bh & 15;
  const int q0 = qt * 128 + w * 32;

  bf16x8 qf[4];
#pragma unroll
  for (int ks = 0; ks < 4; ++ks)
    qf[ks] = *(const bf16x8*)&qb[((size_t)bh * S_ + q0 + q32) * HD_ + ks * 16 + hi * 8];

  const f32x16 z16 = {};
  f32x16 acc[2] = {z16, z16};
  float lrun = 0.f;

  const int srow = l >> 3;
  const int scol = ((l & 7) ^ srow) << 3;
  const u16* kbase = kb  + ((size_t)bh * S_  + w * 16 + srow) * HD_ + scol;
  const u16* vbase = vtb + ((size_t)bh * HD_ + w * 16 + srow) * S_  + scol;

  auto STAGE = [&](int buf, int t) {
#pragma unroll
    for (int s = 0; s < 2; ++s)
#pragma unroll
      for (int j = 0; j < 2; ++j) {
        gload_lds16(kbase + ((size_t)t * 128 + s * 64) * HD_ + j * 8 * HD_,
                    &Kl[buf][s][(w * 16 + j * 8) * 64]);
        gload_lds16(vbase + (size_t)t * 128 + s * 64 + j * 8 * S_,
                    &Vl[buf][s][(w * 16 + j * 8) * 64]);
      }
  };

  STAGE(0, 0);
  __syncthreads();

  const int sw = q32 & 7;

  auto SOFTMAX = [&](f32x16& st0, f32x16& st1, bf16x8* pa) {
#pragma unroll
    for (int kt = 0; kt < 2; ++kt) {
      const f32x16& stt = kt ? st1 : st0;
      float p[16];
#pragma unroll
      for (int r = 0; r < 16; ++r) p[r] = ex2(stt[r]);
#pragma unroll
      for (int g = 0; g < 4; ++g)
        lrun += (p[4 * g] + p[4 * g + 1]) + (p[4 * g + 2] + p[4 * g + 3]);
      u32 wk0[4], wk1[4];
#pragma unroll
      for (int g = 0; g < 4; ++g) {
        wk0[g] = cvtpk(p[4 * g], p[4 * g + 1]);
        wk1[g] = cvtpk(p[4 * g + 2], p[4 * g + 3]);
      }
#pragma unroll
      for (int k2 = 0; k2 < 2; ++k2) {
        u32 a0 = wk0[2 * k2], b0 = wk0[2 * k2 + 1];
        u32 a1 = wk1[2 * k2], b1 = wk1[2 * k2 + 1];
        asm volatile("v_permlane32_swap_b32 %0, %1" : "+v"(a0), "+v"(b0));
        asm volatile("v_permlane32_swap_b32 %0, %1" : "+v"(a1), "+v"(b1));
        uint4 wv = {a0, a1, b0, b1};
        pa[kt * 2 + k2] = __builtin_bit_cast(bf16x8, wv);
      }
    }
  };

  for (int t = 0; t < 16; ++t) {
    const int cur = t & 1;
    if (t + 1 < 16) STAGE(cur ^ 1, t + 1);

    f32x16 stA0 = z16, stA1 = z16, stB0 = z16, stB1 = z16;
    __builtin_amdgcn_s_setprio(1);
#pragma unroll
    for (int ks = 0; ks < 4; ++ks) {
      const int so = ((((ks << 1) | hi) ^ sw) << 3);
      const bf16x8 kfA0 = *(const bf16x8*)&Kl[cur][0][(q32) * 64 + so];
      const bf16x8 kfA1 = *(const bf16x8*)&Kl[cur][0][(32 + q32) * 64 + so];
      const bf16x8 kfB0 = *(const bf16x8*)&Kl[cur][1][(q32) * 64 + so];
      const bf16x8 kfB1 = *(const bf16x8*)&Kl[cur][1][(32 + q32) * 64 + so];
      stA0 = __builtin_amdgcn_mfma_f32_32x32x16_bf16(kfA0, qf[ks], stA0, 0, 0, 0);
      stA1 = __builtin_amdgcn_mfma_f32_32x32x16_bf16(kfA1, qf[ks], stA1, 0, 0, 0);
      stB0 = __builtin_amdgcn_mfma_f32_32x32x16_bf16(kfB0, qf[ks], stB0, 0, 0, 0);
      stB1 = __builtin_amdgcn_mfma_f32_32x32x16_bf16(kfB1, qf[ks], stB1, 0, 0, 0);
    }
    __builtin_amdgcn_s_setprio(0);

    bf16x8 pa[4];
    SOFTMAX(stA0, stA1, pa);
    __builtin_amdgcn_s_setprio(1);
#pragma unroll
    for (int dt = 0; dt < 2; ++dt)
#pragma unroll
      for (int ks = 0; ks < 4; ++ks) {
        const bf16x8 vf = *(const bf16x8*)&Vl[cur][0][(dt * 32 + q32) * 64 + ((((ks << 1) | hi) ^ sw) << 3)];
        acc[dt] = __builtin_amdgcn_mfma_f32_32x32x16_bf16(vf, pa[ks], acc[dt], 0, 0, 0);
      }
    __builtin_amdgcn_s_setprio(0);

    SOFTMAX(stB0, stB1, pa);
    __builtin_amdgcn_s_setprio(1);
#pragma unroll
    for (int dt = 0; dt < 2; ++dt)
#pragma unroll
      for (int ks = 0; ks < 4; ++ks) {
        const bf16x8 vf = *(const bf16x8*)&Vl[cur][1][(dt * 32 + q32) * 64 + ((((ks << 1) | hi) ^ sw) << 3)];
        acc[dt] = __builtin_amdgcn_mfma_f32_32x32x16_bf16(vf, pa[ks], acc[dt], 0, 0, 0);
      }
    __builtin_amdgcn_s_setprio(0);

    __syncthreads();
  }

  lrun += __shfl_xor(lrun, 32);
  const float linv = 1.f / lrun;
  const size_t orow = ((size_t)(bb * S_ + q0 + q32)) * H_ + hh * HD_;
#pragma unroll
  for (int dt = 0; dt < 2; ++dt)
#pragma unroll
    for (int g = 0; g < 4; ++g) {
      const u32 o0 = cvtpk(acc[dt][4 * g] * linv, acc[dt][4 * g + 1] * linv);
      const u32 o1 = cvtpk(acc[dt][4 * g + 2] * linv, acc[dt][4 * g + 3] * linv);
      uint2 ov; ov.x = o0; ov.y = o1;
      *(uint2*)&ob[orow + dt * 32 + g * 8 + hi * 4] = ov;
    }
}

extern "C" void kernel_launch(void* const* d_in, const int* in_sizes, int n_in,
                              void* d_out, int out_size, void* d_ws, size_t ws_size,
                              hipStream_t stream) {
  const float* x     = (const float*)d_in[0];
  const float* qkv_w = (const float*)d_in[1];
  const float* qkv_b = (const float*)d_in[2];
  const float* out_w = (const float*)d_in[3];
  const float* out_b = (const float*)d_in[4];

  char* ws = (char*)d_ws;
  u16* xb    = (u16*)(ws);              // 8 MB
  u16* wqkvb = (u16*)(ws + 8388608);    // 6 MB
  u16* wob   = (u16*)(ws + 14680064);   // 2 MB
  u16* qb    = (u16*)(ws + 16777216);   // 8 MB
  u16* kb    = (u16*)(ws + 25165824);   // 8 MB
  u16* vtb   = (u16*)(ws + 33554432);   // 8 MB (V transposed [b,h,d,s], written by gemm_qkv)
  u16* ob    = (u16*)(ws + 41943040);   // 8 MB -> 48 MB total

  cvt_all<<<8192, 256, 0, stream>>>(x, qkv_w, out_w, xb, wqkvb, wob);

  gemm_qkv<<<512, 256, 0, stream>>>(xb, wqkvb, qkv_b, qb, kb, vtb);
  attn_fwd<<<512, 256, 0, stream>>>(qb, kb, vtb, ob);
  gemm_out<<<512, 256, 0, stream>>>(ob, wob, out_b, (float*)d_out);
}